// Round 15
// baseline (547.145 us; speedup 1.0000x reference)
//
#include <hip/hip_runtime.h>
#include <math.h>

// ---------------------------------------------------------------------------
// Net_LV Monte-Carlo local-vol simulation, MI355X (gfx950)  — MFMA version 10
// 512 blocks x 512 threads (2 blocks/CU): per 16-path group a PRODUCER wave
// (diff net, S update, path/varp writes) and a CONSUMER wave (vv/ve/vOut/
// eOut, cvv/cve, accCur, reductions); 4 pairs per block. 16 waves/CU.
// Cross-wave handoff: d via 8-deep LDS ring + monotonic flag; consumer
// recomputes gg and S bit-identically. No block barriers in the step loop.
// v10: LDS cut to ~71KB (weight-staging overlaid with act buffers) so two
// 512-thread blocks co-reside -> 4 waves/SIMD at the 128-VGPR cap that
// TPB=512 actually gets (TPB=1024 was hard-capped at 64 VGPR -> spill).
// ---------------------------------------------------------------------------

#define TPB 512
#define NBLK 512
#define MC 32768
#define NSTEPS 90
#define NGRID 91
#define RATEf 0.025f

typedef _Float16 f16;
typedef f16 f16x8 __attribute__((ext_vector_type(8)));
typedef f16 f16x4 __attribute__((ext_vector_type(4)));
typedef float f32x4 __attribute__((ext_vector_type(4)));

#define CFENCE() asm volatile("" ::: "memory")

__device__ __forceinline__ float fast_rcp(float x) {
  float r; asm("v_rcp_f32 %0, %1" : "=v"(r) : "v"(x)); return r;
}

__device__ __forceinline__ void wait_ge(volatile int* f, int t) {
  while (*f < t) __builtin_amdgcn_s_sleep(1);
}

// ---- d_out offsets (float elements), in reference return order ----
#define PATH_OFF   0
#define VARP_OFF   (MC*NGRID)
#define DL_OFF     (2*MC*NGRID)
#define PV_OFF     (2*MC*NGRID + MC)
#define VV_OFF     (PV_OFF + 63)
#define EP_OFF     (VV_OFF + 63)
#define MEAN_OFF   (EP_OFF + MC)
#define VAR_OFF    (MEAN_OFF + 1)
#define ERR_OFF    (VAR_OFF + 1)

// ---- workspace (doubles) ----
#define WS_STRIDE  132
#define MEANE_SLOT (NBLK*WS_STRIDE)

// ---- LDS f32 offsets (dwords) ----
enum : int {
  OFF_DW0 = 0,     // diff Wi t-row, padded 64
  OFF_DW1 = 64,
  OFF_DBI = 128,
  OFF_DWO = 192,
  OFF_DBH = 256,   // 3*64
  OFF_VW0 = 448,   // padded 32
  OFF_VW1 = 480,
  OFF_VBI = 512,
  OFF_VBH = 544,   // 2*32
  OFF_VBO = 608,   // 64
  OFF_EBI = 672,   // 32
  OFF_EBH = 704,   // 2*32
  OFF_EWO = 768,   // 32
  OFF_SC  = 800,   // [0]=dbo, [1]=ebo  (pad to 804)
  OFF_EWI = 804,   // f32 CURRENT-PERIOD slice [92][20]=1840 (+32 pad)
  OFF_PSUM= 2676,  // 4 pairs * 42 doubles = 336 dw
  OFF_ESUM= 3012,  // 4 pairs * 4 doubles = 32 dw
  OFF_DTAB= 3044,  // 91 discounts (+1 pad)
  OFF_PH  = 3136,  // 4 pairs * [16][62] f32 path history = 3968 dw
  OFF_DRING=7104,  // 4 pairs * 8 slots * 16 paths = 512 dw
  OFF_FLAGS=7616,  // 4 pairs * 16 (producer progress)
  OFF_CONS =7680,  // 4 pairs * 16 (consumer progress)
  F16BASE = 7744
};
// ---- f16 offsets (units of f16, relative to smh) ----
// persistent: diff layer 2 only. staging (consumed into regs at period start)
// OVERLAYS the per-pair act buffers (dead across period boundaries).
enum : int {
  L2_F   = 0,        // diff layer 2 [64][64] = 4096 (persistent; producer LDS)
  STG_F  = 4096,     // staging base == act base (overlay)
  VWH_S  = 12288,    // staging: 2 * [32][40]
  EWH_S  = 14848,    // staging: 2 * [32][40]
  VWO_S  = 17408     // staging: [64][40]  (end 19968)
};
#define SMEM_DW   17728
#define SMEM_BYTES (SMEM_DW*4)

__device__ __forceinline__ float softplus_f(float x) {
  return fmaxf(x, 0.0f) + __logf(1.0f + __expf(-fabsf(x)));
}

// ---- diff hidden layer: A in regs (single f16), B 2-term hi/lo from LDS ----
__device__ __forceinline__ void mfma_hidden_r(
    const f16x8 (&A)[4][2], f16* acth, f16* actl,
    const float* __restrict__ bias, int p, int g)
{
  f16x8 Bh[2], Bl[2];
#pragma unroll
  for (int kt = 0; kt < 2; ++kt) {
    const int bi = p*72 + 32*kt + 8*g;
    Bh[kt] = *(const f16x8*)&acth[bi];
    Bl[kt] = *(const f16x8*)&actl[bi];
  }
  f32x4 acc[4];
#pragma unroll
  for (int mt = 0; mt < 4; ++mt)
    acc[mt] = *(const f32x4*)&bias[16*mt + 4*g];
#pragma unroll
  for (int mt = 0; mt < 4; ++mt) {
#pragma unroll
    for (int kt = 0; kt < 2; ++kt) {
      acc[mt] = __builtin_amdgcn_mfma_f32_16x16x32_f16(A[mt][kt], Bl[kt], acc[mt], 0,0,0);
      acc[mt] = __builtin_amdgcn_mfma_f32_16x16x32_f16(A[mt][kt], Bh[kt], acc[mt], 0,0,0);
    }
  }
  CFENCE();
#pragma unroll
  for (int mt = 0; mt < 4; ++mt) {
    f16x4 vh, vl;
#pragma unroll
    for (int r = 0; r < 4; ++r) {
      const float x = fmaxf(acc[mt][r], 0.0f);
      const f16 h = (f16)x;
      vh[r] = h;
      vl[r] = (f16)(x - (float)h);
    }
    const int wi = p*72 + 16*mt + 4*g;
    *(f16x4*)&acth[wi] = vh;
    *(f16x4*)&actl[wi] = vl;
  }
  CFENCE();
}

// ---- same but A fragments read from LDS (layer 2, saves producer VGPRs) ----
__device__ __forceinline__ void mfma_hidden_l(
    const f16* __restrict__ Ab, f16* acth, f16* actl,
    const float* __restrict__ bias, int p, int g)
{
  f16x8 Bh[2], Bl[2];
#pragma unroll
  for (int kt = 0; kt < 2; ++kt) {
    const int bi = p*72 + 32*kt + 8*g;
    Bh[kt] = *(const f16x8*)&acth[bi];
    Bl[kt] = *(const f16x8*)&actl[bi];
  }
  f32x4 acc[4];
#pragma unroll
  for (int mt = 0; mt < 4; ++mt)
    acc[mt] = *(const f32x4*)&bias[16*mt + 4*g];
#pragma unroll
  for (int mt = 0; mt < 4; ++mt) {
#pragma unroll
    for (int kt = 0; kt < 2; ++kt) {
      const f16x8 a = *(const f16x8*)&Ab[(p + 16*mt)*64 + 32*kt + 8*g];
      acc[mt] = __builtin_amdgcn_mfma_f32_16x16x32_f16(a, Bl[kt], acc[mt], 0,0,0);
      acc[mt] = __builtin_amdgcn_mfma_f32_16x16x32_f16(a, Bh[kt], acc[mt], 0,0,0);
    }
  }
  CFENCE();
#pragma unroll
  for (int mt = 0; mt < 4; ++mt) {
    f16x4 vh, vl;
#pragma unroll
    for (int r = 0; r < 4; ++r) {
      const float x = fmaxf(acc[mt][r], 0.0f);
      const f16 h = (f16)x;
      vh[r] = h;
      vl[r] = (f16)(x - (float)h);
    }
    const int wi = p*72 + 16*mt + 4*g;
    *(f16x4*)&acth[wi] = vh;
    *(f16x4*)&actl[wi] = vl;
  }
  CFENCE();
}

__device__ __forceinline__ void diff_L1(const float* sm, f16* acth, f16* actl,
                                        float tp, float Sp, int p, int g)
{
  const int j0 = 16*g;
  f16x8 vh0, vh1, vl0, vl1;
#pragma unroll
  for (int c = 0; c < 4; ++c) {
    const f32x4 w0 = *(const f32x4*)&sm[OFF_DW0 + j0 + 4*c];
    const f32x4 w1 = *(const f32x4*)&sm[OFF_DW1 + j0 + 4*c];
    const f32x4 bi = *(const f32x4*)&sm[OFF_DBI + j0 + 4*c];
#pragma unroll
    for (int r = 0; r < 4; ++r) {
      const float x = fmaxf(fmaf(w0[r], tp, fmaf(w1[r], Sp, bi[r])), 0.0f);
      const f16 h = (f16)x;
      const f16 l = (f16)(x - (float)h);
      if (c < 2) { vh0[c*4+r] = h; vl0[c*4+r] = l; }
      else       { vh1[(c-2)*4+r] = h; vl1[(c-2)*4+r] = l; }
    }
  }
  const int wi0 = p*72 + j0;
  const int wi1 = wi0 + 8;
  *(f16x8*)&acth[wi0] = vh0; *(f16x8*)&acth[wi1] = vh1;
  *(f16x8*)&actl[wi0] = vl0; *(f16x8*)&actl[wi1] = vl1;
  CFENCE();
}

__device__ __forceinline__ float diff_out(const float* sm, const f16* acth,
                                          const f16* actl, int p, int g)
{
  const int kb = 16*g;
  const f16x8 h0 = *(const f16x8*)&acth[p*72 + kb];
  const f16x8 h1 = *(const f16x8*)&acth[p*72 + kb + 8];
  const f16x8 l0 = *(const f16x8*)&actl[p*72 + kb];
  const f16x8 l1 = *(const f16x8*)&actl[p*72 + kb + 8];
  float s = 0.0f;
#pragma unroll
  for (int e = 0; e < 8; ++e) {
    s = fmaf((float)h0[e] + (float)l0[e], sm[OFF_DWO + kb + e], s);
    s = fmaf((float)h1[e] + (float)l1[e], sm[OFF_DWO + kb + 8 + e], s);
  }
  s += __shfl_xor(s, 16); s += __shfl_xor(s, 32);
  return softplus_f(s + sm[OFF_SC]);
}

// ---- paired small-net hidden layer (vv & ve together, A in regs) ----
__device__ __forceinline__ void small_pair_r(
    const f16x8 (&Av)[2], const f16x8 (&Ae)[2],
    f16* vvact, f16* veact,
    const float* __restrict__ vb, const float* __restrict__ eb,
    int p, int g)
{
  const int bi = p*40 + 8*g;
  const f16x8 Bv = *(const f16x8*)&vvact[bi];
  const f16x8 Be = *(const f16x8*)&veact[bi];
  f32x4 av[2], ae[2];
#pragma unroll
  for (int mt = 0; mt < 2; ++mt) {
    av[mt] = __builtin_amdgcn_mfma_f32_16x16x32_f16(Av[mt], Bv,
             *(const f32x4*)&vb[16*mt + 4*g], 0,0,0);
    ae[mt] = __builtin_amdgcn_mfma_f32_16x16x32_f16(Ae[mt], Be,
             *(const f32x4*)&eb[16*mt + 4*g], 0,0,0);
  }
  CFENCE();
#pragma unroll
  for (int mt = 0; mt < 2; ++mt) {
    f16x4 xv, xe;
#pragma unroll
    for (int r = 0; r < 4; ++r) {
      xv[r] = (f16)fmaxf(av[mt][r], 0.0f);
      xe[r] = (f16)fmaxf(ae[mt][r], 0.0f);
    }
    const int wi = p*40 + 16*mt + 4*g;
    *(f16x4*)&vvact[wi] = xv;
    *(f16x4*)&veact[wi] = xe;
  }
  CFENCE();
}

__device__ void load_weights(float* sm, f16* smh, int m, int tid,
  const float* dWi, const float* dbi_g, const float* dWh_g, const float* dbh_g,
  const float* dWo_g, const float* dbo_g,
  const float* vWi, const float* vbi_g, const float* vWh_g, const float* vbh_g,
  const float* vWo_g, const float* vbo_g,
  const float* eWi, const float* ebi_g, const float* eWh_g, const float* ebh_g,
  const float* eWo_g, const float* ebo_g)
{
  for (int j = tid; j < 64; j += TPB) {
    sm[OFF_DW0+j] = (j<50) ? dWi[m*100 + j]      : 0.0f;
    sm[OFF_DW1+j] = (j<50) ? dWi[m*100 + 50 + j] : 0.0f;
    sm[OFF_DBI+j] = (j<50) ? dbi_g[m*50 + j]     : 0.0f;
    sm[OFF_DWO+j] = (j<50) ? dWo_g[m*50 + j]     : 0.0f;
  }
  for (int idx = tid; idx < 192; idx += TPB) {
    const int l = idx >> 6, j = idx & 63;
    sm[OFF_DBH+idx] = (j<50) ? dbh_g[(m*3+l)*50 + j] : 0.0f;
  }
  for (int j = tid; j < 32; j += TPB) {
    sm[OFF_VW0+j] = (j<30) ? vWi[m*60 + j]      : 0.0f;
    sm[OFF_VW1+j] = (j<30) ? vWi[m*60 + 30 + j] : 0.0f;
    sm[OFF_VBI+j] = (j<30) ? vbi_g[m*30 + j]    : 0.0f;
    sm[OFF_EBI+j] = (j<20) ? ebi_g[m*20 + j]    : 0.0f;
    sm[OFF_EWO+j] = (j<20) ? eWo_g[m*20 + j]    : 0.0f;
  }
  for (int idx = tid; idx < 64; idx += TPB) {
    const int l = idx >> 5, j = idx & 31;
    sm[OFF_VBH+idx] = (j<30) ? vbh_g[(m*2+l)*30 + j] : 0.0f;
    sm[OFF_EBH+idx] = (j<20) ? ebh_g[(m*2+l)*20 + j] : 0.0f;
  }
  for (int j = tid; j < 64; j += TPB)
    sm[OFF_VBO+j] = (j<63) ? vbo_g[m*63 + j] : 0.0f;
  if (tid == 0) { sm[OFF_SC] = dbo_g[m]; sm[OFF_SC+1] = ebo_g[m]; }

  // EWI slice for period m ([92][20])
  for (int idx = tid; idx < 1840; idx += TPB)
    sm[OFF_EWI + idx] = eWi[m*1840 + idx];

  // diff hidden weights -> single f16, A[j][k] = W[k][j]:
  // layers 0,1 -> staging (consumed to regs); layer 2 -> persistent L2_F
  for (int idx = tid; idx < 12288; idx += TPB) {
    const int l = idx >> 12, j = (idx >> 6) & 63, k = idx & 63;
    const float w = (j<50 && k<50) ? dWh_g[((m*3+l)*50 + k)*50 + j] : 0.0f;
    const int dst = (l == 2) ? (L2_F + (idx & 4095)) : (STG_F + idx);
    smh[dst] = (f16)w;
  }
  // vv & ve hidden: A[j][k] single f16, [32][40] (staging)
  for (int idx = tid; idx < 2560; idx += TPB) {
    const int l = idx / 1280, r = idx % 1280, j = r / 40, k = r % 40;
    smh[VWH_S + idx] = (f16)((j<30 && k<30) ? vWh_g[((m*2+l)*30 + k)*30 + j] : 0.0f);
    smh[EWH_S + idx] = (f16)((j<20 && k<20) ? eWh_g[((m*2+l)*20 + k)*20 + j] : 0.0f);
  }
  // vOut: A[s][k] = vWo[k][s], [64][40] single f16 (staging)
  for (int idx = tid; idx < 2560; idx += TPB) {
    const int s = idx / 40, k = idx % 40;
    smh[VWO_S + idx] = (f16)((s<63 && k<30) ? vWo_g[(m*30 + k)*63 + s] : 0.0f);
  }
}

extern "C" __global__ void __launch_bounds__(TPB, 2)
sim_kernel(const float* __restrict__ S0g, const float* __restrict__ zg,
           const float* dWi, const float* dbi_g, const float* dWh_g,
           const float* dbh_g, const float* dWo_g, const float* dbo_g,
           const float* vWi, const float* vbi_g, const float* vWh_g,
           const float* vbh_g, const float* vWo_g, const float* vbo_g,
           const float* eWi, const float* ebi_g, const float* eWh_g,
           const float* ebh_g, const float* eWo_g, const float* ebo_g,
           float* __restrict__ out, double* __restrict__ wsd)
{
  extern __shared__ float sm[];
  f16* smh = (f16*)&sm[F16BASE];
  const int tid  = threadIdx.x;
  const int wv   = tid >> 6;
  const int lane = tid & 63;
  const int q    = wv & 3;            // pair (16-path group) 0..3
  const int role = wv >> 2;           // 0 = producer (diff), 1 = consumer
  const int p    = lane & 15;
  const int g    = lane >> 4;
  f16* acth  = smh + STG_F + q*3584;  // overlays staging (dead after frag load)
  f16* actl  = acth + 1152;
  f16* vvact = acth + 2304;
  f16* veact = acth + 2944;
  float* ph    = sm + OFF_PH + q*992;
  float* dring = sm + OFF_DRING + q*128;
  volatile int* prodF = (volatile int*)(sm + OFF_FLAGS) + q*16;
  volatile int* consF = (volatile int*)(sm + OFF_CONS) + q*16;
  const int P0 = blockIdx.x*64 + q*16;
  const float S0v = S0g[0];

  for (int j = tid; j < 91; j += TPB)
    sm[OFF_DTAB + j] = expf(-RATEf * (0.01f * (float)j));
  if (tid < 4) {
    ((int*)(sm + OFF_FLAGS))[tid*16] = 0;
    ((int*)(sm + OFF_CONS))[tid*16]  = 0;
  }
  if (role == 0 && g == 0)
    out[PATH_OFF + (size_t)(P0 + p) * NGRID + 0] = S0v;
  if (role == 0) __builtin_amdgcn_s_setprio(1);

  // producer state
  float S = S0v;
  // consumer state
  float S_prev = S0v, rmax = S0v, cve = 0.0f;
  f32x4 cvv[4];
#pragma unroll
  for (int mt = 0; mt < 4; ++mt) cvv[mt] = (f32x4){0.f,0.f,0.f,0.f};
  float accCur[8];

  // persistent register A-fragments (reloaded per period)
  f16x8 dA[2][4][2];                  // producer
  f16x8 vA1[2], vA2[2], eA1[2], eA2[2], oA[4];  // consumer

  for (int m = 0; m < 3; ++m) {
    __syncthreads();   // prior period fully consumed; staging/act reload safe
    load_weights(sm, smh, m, tid, dWi, dbi_g, dWh_g, dbh_g, dWo_g, dbo_g,
                 vWi, vbi_g, vWh_g, vbh_g, vWo_g, vbo_g,
                 eWi, ebi_g, eWh_g, ebh_g, eWo_g, ebo_g);
    __syncthreads();

    // ---- staging -> registers (no act writes allowed yet) ----
    if (role == 0) {
#pragma unroll
      for (int l = 0; l < 2; ++l)
#pragma unroll
        for (int mt = 0; mt < 4; ++mt)
#pragma unroll
          for (int kt = 0; kt < 2; ++kt)
            dA[l][mt][kt] = *(const f16x8*)
                &smh[STG_F + l*4096 + (p + 16*mt)*64 + 32*kt + 8*g];
    } else {
#pragma unroll
      for (int mt = 0; mt < 2; ++mt) {
        vA1[mt] = *(const f16x8*)&smh[VWH_S +        (p + 16*mt)*40 + 8*g];
        vA2[mt] = *(const f16x8*)&smh[VWH_S + 1280 + (p + 16*mt)*40 + 8*g];
        eA1[mt] = *(const f16x8*)&smh[EWH_S +        (p + 16*mt)*40 + 8*g];
        eA2[mt] = *(const f16x8*)&smh[EWH_S + 1280 + (p + 16*mt)*40 + 8*g];
      }
#pragma unroll
      for (int mt = 0; mt < 4; ++mt)
        oA[mt] = *(const f16x8*)&smh[VWO_S + (p + 16*mt)*40 + 8*g];

      // accCur for period m from path history (bit-identical k-order)
#pragma unroll
      for (int e = 0; e < 8; ++e)
        accCur[e] = S0v * sm[OFF_EWI + 20 + 8*g + e];
      const int kmax = 30*m;
      for (int k = 1; k <= kmax; ++k) {
        const float Sk = ph[p*62 + k];
        const int ro = (1 + k)*20 + 8*g;
        const f32x4 w0 = *(const f32x4*)&sm[OFF_EWI + ro];
        const f32x4 w1 = *(const f32x4*)&sm[OFF_EWI + ro + 4];
#pragma unroll
        for (int e = 0; e < 4; ++e) {
          accCur[e]   = fmaf(Sk, w0[e], accCur[e]);
          accCur[e+4] = fmaf(Sk, w1[e], accCur[e+4]);
        }
      }
    }
    __syncthreads();   // staging dead -> act buffers may be written

    if (role == 0) {
      if (m == 0) {
        diff_L1(sm, acth, actl, 0.0f, S, p, g);
        mfma_hidden_r(dA[0], acth, actl, sm + OFF_DBH,       p, g);
        mfma_hidden_r(dA[1], acth, actl, sm + OFF_DBH + 64,  p, g);
        mfma_hidden_l(smh + L2_F, acth, actl, sm + OFF_DBH + 128, p, g);
        const float d0 = diff_out(sm, acth, actl, p, g);
        if (g == 0)
          out[VARP_OFF + (size_t)(P0 + p) * NGRID + 0] = d0 * d0;
        CFENCE();
      }

      for (int it = 1; it <= 30; ++it) {
        const int i = m*30 + it;
        const float ti = 0.01f * (float)i;
        const float tp = 0.01f * (float)(i - 1);
        const float hstep = ti - tp;
        const float sqh = sqrtf(hstep);
        const float zval = zg[(size_t)(P0 + p) * NSTEPS + (i - 1)];
        const float dWv = sqh * zval;

        diff_L1(sm, acth, actl, tp, S, p, g);
        mfma_hidden_r(dA[0], acth, actl, sm + OFF_DBH,       p, g);
        mfma_hidden_r(dA[1], acth, actl, sm + OFF_DBH + 64,  p, g);
        mfma_hidden_l(smh + L2_F, acth, actl, sm + OFF_DBH + 128, p, g);
        const float d = diff_out(sm, acth, actl, p, g);
        if (g == 0) {
          out[VARP_OFF + (size_t)(P0 + p) * NGRID + i] = d * d;
          if (i == NSTEPS) out[DL_OFF + (P0 + p)] = d;
        }

        // publish d (ring depth 8, back-pressure on consumer progress)
        if (i > 8) wait_ge(consF, i - 8);
        CFENCE();
        if (g == 0) dring[(i & 7)*16 + p] = d;
        asm volatile("s_waitcnt lgkmcnt(0)" ::: "memory");
        if (lane == 0) *prodF = i;

        // state update
        const float Sold = S;
        const float t1_ = (RATEf*Sold*hstep) * fast_rcp(1.0f + (RATEf*Sold)*sqh);
        const float t2_ = ((Sold*d)*dWv)     * fast_rcp(1.0f + (Sold*d)*sqh);
        const float Snew = (Sold + t1_) + t2_;
        S = Snew;
        if (g == 0)
          out[PATH_OFF + (size_t)(P0 + p) * NGRID + i] = Snew;
      }
    } else {
      for (int it = 1; it <= 30; ++it) {
        const int i = m*30 + it;
        const float ti = 0.01f * (float)i;
        const float tp = 0.01f * (float)(i - 1);
        const float hstep = ti - tp;
        const float sqh = sqrtf(hstep);
        const float disc = sm[OFF_DTAB + (i - 1)];
        const float zval = zg[(size_t)(P0 + p) * NSTEPS + (i - 1)];
        const float dWv = sqh * zval;

        // d-independent work first
        { // vL1
          const int j0 = 8*g;
          f16x8 vh;
#pragma unroll
          for (int c = 0; c < 2; ++c) {
            const f32x4 w0 = *(const f32x4*)&sm[OFF_VW0 + j0 + 4*c];
            const f32x4 w1 = *(const f32x4*)&sm[OFF_VW1 + j0 + 4*c];
            const f32x4 bi = *(const f32x4*)&sm[OFF_VBI + j0 + 4*c];
#pragma unroll
            for (int r = 0; r < 4; ++r)
              vh[c*4+r] = (f16)fmaxf(fmaf(w0[r], tp, fmaf(w1[r], S_prev, bi[r])), 0.0f);
          }
          *(f16x8*)&vvact[p*40 + j0] = vh;
        }
        { // eL1 (rows >=20 hit zero A-pads)
          const int j0 = 8*g;
          const f32x4 t0 = *(const f32x4*)&sm[OFF_EWI + j0];
          const f32x4 t1 = *(const f32x4*)&sm[OFF_EWI + j0 + 4];
          const f32x4 b0 = *(const f32x4*)&sm[OFF_EBI + j0];
          const f32x4 b1 = *(const f32x4*)&sm[OFF_EBI + j0 + 4];
          f16x8 vh;
#pragma unroll
          for (int e = 0; e < 8; ++e) {
            const float wt = (e < 4) ? t0[e] : t1[e-4];
            const float bb = (e < 4) ? b0[e] : b1[e-4];
            vh[e] = (f16)fmaxf(fmaf(wt, tp, accCur[e] + bb), 0.0f);
          }
          *(f16x8*)&veact[p*40 + j0] = vh;
        }
        CFENCE();
        small_pair_r(vA1, eA1, vvact, veact, sm + OFF_VBH,      sm + OFF_EBH,      p, g);
        small_pair_r(vA2, eA2, vvact, veact, sm + OFF_VBH + 32, sm + OFF_EBH + 32, p, g);

        f32x4 vacc[4];
        {
          const f16x8 Bv = *(const f16x8*)&vvact[p*40 + 8*g];
#pragma unroll
          for (int mt = 0; mt < 4; ++mt)
            vacc[mt] = __builtin_amdgcn_mfma_f32_16x16x32_f16(
                oA[mt], Bv, *(const f32x4*)&sm[OFF_VBO + 16*mt + 4*g], 0,0,0);
        }
        float eouts;
        {
          const int kb = 8*g;
          const f16x8 h = *(const f16x8*)&veact[p*40 + kb];
          float s_ = 0.0f;
#pragma unroll
          for (int e = 0; e < 8; ++e)
            s_ = fmaf((float)h[e], sm[OFF_EWO + kb + e], s_);
          s_ += __shfl_xor(s_, 16); s_ += __shfl_xor(s_, 32);
          eouts = s_ + sm[OFF_SC + 1];
        }

        // now need d
        wait_ge(prodF, i);
        CFENCE();
        const float d = dring[(i & 7)*16 + p];
        const float gg = ((disc * S_prev) * d) * dWv;
#pragma unroll
        for (int mt = 0; mt < 4; ++mt)
#pragma unroll
          for (int r = 0; r < 4; ++r)
            cvv[mt][r] = fmaf(gg, vacc[mt][r], cvv[mt][r]);
        cve = fmaf(gg, eouts, cve);

        // S update (bit-identical to producer)
        const float Sold = S_prev;
        const float t1_ = (RATEf*Sold*hstep) * fast_rcp(1.0f + (RATEf*Sold)*sqh);
        const float t2_ = ((Sold*d)*dWv)     * fast_rcp(1.0f + (Sold*d)*sqh);
        const float Snew = (Sold + t1_) + t2_;
        rmax = fmaxf(rmax, Snew);
        if (g == 0 && i <= 60) ph[p*62 + i] = Snew;
        { // accCur update with slice row (1+i)
          const int ro = (1 + i)*20 + 8*g;
          const f32x4 a0 = *(const f32x4*)&sm[OFF_EWI + ro];
          const f32x4 a1 = *(const f32x4*)&sm[OFF_EWI + ro + 4];
#pragma unroll
          for (int e = 0; e < 4; ++e) {
            accCur[e]   = fmaf(Snew, a0[e], accCur[e]);
            accCur[e+4] = fmaf(Snew, a1[e], accCur[e+4]);
          }
        }
        S_prev = Snew;
        CFENCE();
        if (lane == 0) *consF = i;
      }

      // ---- period-end price partials (consumer) ----
      {
        const float discm = sm[OFF_DTAB + 30*(m+1)];
        double* ps = (double*)&sm[OFF_PSUM];
#pragma unroll
        for (int mt = 0; mt < 4; ++mt) {
#pragma unroll
          for (int r = 0; r < 4; ++r) {
            const int s = 16*mt + 4*g + r;
            const bool act = (s >= 21*m) && (s < 21*m + 21);
            double s1 = 0.0, s2 = 0.0;
            if (act) {
              const float Kst = 0.8f + 0.02f * (float)(s - 21*m);
              const float pr_ = discm * fmaxf(S_prev - Kst, 0.0f) - cvv[mt][r];
              s1 = (double)pr_;
              s2 = (double)pr_ * (double)pr_;
            }
            s1 += __shfl_xor(s1, 1); s1 += __shfl_xor(s1, 2);
            s1 += __shfl_xor(s1, 4); s1 += __shfl_xor(s1, 8);
            s2 += __shfl_xor(s2, 1); s2 += __shfl_xor(s2, 2);
            s2 += __shfl_xor(s2, 4); s2 += __shfl_xor(s2, 8);
            if (act && p == 0) {
              const int sI = s - 21*m;
              ps[q*42 + sI*2 + 0] = s1;
              ps[q*42 + sI*2 + 1] = s2;
            }
          }
        }
      }
    } // role

    __syncthreads();
    if (tid < 21) {
      double* ps = (double*)&sm[OFF_PSUM];
      double a = 0.0, b = 0.0;
      for (int w = 0; w < 4; ++w) { a += ps[w*42 + tid*2]; b += ps[w*42 + tid*2 + 1]; }
      wsd[(size_t)blockIdx.x*WS_STRIDE + (m*21+tid)*2 + 0] = a;
      wsd[(size_t)blockIdx.x*WS_STRIDE + (m*21+tid)*2 + 1] = b;
    }
  } // periods

  // ---------------- exotic outputs & partials (consumer waves) ----------------
  if (role == 1) {
    const float discT = sm[OFF_DTAB + 90];
    const float e  = discT * (rmax - S_prev);
    const float ep = e - cve;
    if (g == 0) out[EP_OFF + (P0 + p)] = ep;
    double de  = (g == 0) ? (double)e  : 0.0;
    double dp  = (g == 0) ? (double)ep : 0.0;
    double dp2 = (g == 0) ? (double)ep * (double)ep : 0.0;
#pragma unroll
    for (int msk = 1; msk <= 32; msk <<= 1) {
      de  += __shfl_xor(de,  msk);
      dp  += __shfl_xor(dp,  msk);
      dp2 += __shfl_xor(dp2, msk);
    }
    double* es = (double*)&sm[OFF_ESUM];
    if (lane == 0) { es[q*4+0] = de; es[q*4+1] = dp; es[q*4+2] = dp2; }
  }
  __syncthreads();
  if (tid == 0) {
    double* es = (double*)&sm[OFF_ESUM];
    double a = 0, b = 0, c = 0;
    for (int w = 0; w < 4; ++w) { a += es[w*4]; b += es[w*4+1]; c += es[w*4+2]; }
    wsd[(size_t)blockIdx.x*WS_STRIDE + 126] = a;
    wsd[(size_t)blockIdx.x*WS_STRIDE + 127] = b;
    wsd[(size_t)blockIdx.x*WS_STRIDE + 128] = c;
  }
}

extern "C" __global__ void finalize_kernel(double* __restrict__ wsd,
                                           float* __restrict__ out)
{
  const int t = threadIdx.x;
  if (t < 63) {
    double a = 0.0, b = 0.0;
    for (int blk = 0; blk < NBLK; ++blk) {
      a += wsd[(size_t)blk*WS_STRIDE + t*2 + 0];
      b += wsd[(size_t)blk*WS_STRIDE + t*2 + 1];
    }
    const double mean = a / (double)MC;
    const double var  = (b - a*a/(double)MC) / (double)(MC - 1);
    out[PV_OFF + t] = (float)mean;
    out[VV_OFF + t] = (float)var;
  } else if (t == 64) {
    double a = 0.0;
    for (int blk = 0; blk < NBLK; ++blk) a += wsd[(size_t)blk*WS_STRIDE + 126];
    wsd[MEANE_SLOT] = a / (double)MC;
  } else if (t == 65) {
    double a = 0.0, c = 0.0;
    for (int blk = 0; blk < NBLK; ++blk) {
      a += wsd[(size_t)blk*WS_STRIDE + 127];
      c += wsd[(size_t)blk*WS_STRIDE + 128];
    }
    out[MEAN_OFF] = (float)(a / (double)MC);
    out[VAR_OFF]  = (float)((c - a*a/(double)MC) / (double)(MC - 1));
  }
}

extern "C" __global__ void error_kernel(const double* __restrict__ wsd,
                                        float* __restrict__ out)
{
  const int pth = blockIdx.x * 256 + threadIdx.x;
  if (pth < MC) {
    const float meanE = (float)wsd[MEANE_SLOT];
    out[ERR_OFF + pth] = out[EP_OFF + pth] - meanE;
  }
}

extern "C" void kernel_launch(void* const* d_in, const int* in_sizes, int n_in,
                              void* d_out, int out_size, void* d_ws, size_t ws_size,
                              hipStream_t stream)
{
  (void)in_sizes; (void)n_in; (void)out_size; (void)ws_size;
  const float* S0g  = (const float*)d_in[0];
  const float* zg   = (const float*)d_in[1];
  // d_in[2..4] = MC_samples / ind_T / period_length (fixed constants)
  const float* dWi  = (const float*)d_in[5];
  const float* dbi  = (const float*)d_in[6];
  const float* dWh  = (const float*)d_in[7];
  const float* dbh  = (const float*)d_in[8];
  const float* dWo  = (const float*)d_in[9];
  const float* dbo  = (const float*)d_in[10];
  const float* vWi  = (const float*)d_in[11];
  const float* vbi  = (const float*)d_in[12];
  const float* vWh  = (const float*)d_in[13];
  const float* vbh  = (const float*)d_in[14];
  const float* vWo  = (const float*)d_in[15];
  const float* vbo  = (const float*)d_in[16];
  const float* eWi  = (const float*)d_in[17];
  const float* ebi  = (const float*)d_in[18];
  const float* eWh  = (const float*)d_in[19];
  const float* ebh  = (const float*)d_in[20];
  const float* eWo  = (const float*)d_in[21];
  const float* ebo  = (const float*)d_in[22];
  float* out  = (float*)d_out;
  double* wsd = (double*)d_ws;

  hipFuncSetAttribute(reinterpret_cast<const void*>(sim_kernel),
                      hipFuncAttributeMaxDynamicSharedMemorySize, SMEM_BYTES);

  sim_kernel<<<NBLK, TPB, SMEM_BYTES, stream>>>(
      S0g, zg, dWi, dbi, dWh, dbh, dWo, dbo,
      vWi, vbi, vWh, vbh, vWo, vbo,
      eWi, ebi, eWh, ebh, eWo, ebo, out, wsd);
  finalize_kernel<<<1, 128, 0, stream>>>(wsd, out);
  error_kernel<<<MC/256, 256, 0, stream>>>(wsd, out);
}

// Round 16
// 433.938 us; speedup vs baseline: 1.2609x; 1.2609x over previous
//
#include <hip/hip_runtime.h>
#include <math.h>

// ---------------------------------------------------------------------------
// Net_LV Monte-Carlo local-vol simulation, MI355X (gfx950)  — MFMA version 11
// 256 blocks x 512 threads (R10 structure: 8 independent waves x 16 paths,
// no step-loop barriers). v11 cuts LDS-pipe traffic ~25%:
//  - biases folded into MFMA A-matrices via a constant-1.0 activation k-slot
//    (diff: slot 50; small nets: slot 31) -> no bias C-init LDS reads
//  - diff/e output dots computed as row-0 MFMAs (A=DWO/EWO in regs, dbo/ebo
//    in the bias slot) + one shfl broadcast -> no scalar LDS dot reads
//  - diff A layers 0,1 in regs; layer 2 from LDS (register rebalance)
// ---------------------------------------------------------------------------

#define TPB 512
#define NBLK 256
#define MC 32768
#define NSTEPS 90
#define NGRID 91
#define RATEf 0.025f

typedef _Float16 f16;
typedef f16 f16x8 __attribute__((ext_vector_type(8)));
typedef f16 f16x4 __attribute__((ext_vector_type(4)));
typedef float f32x4 __attribute__((ext_vector_type(4)));

#define CFENCE() asm volatile("" ::: "memory")

__device__ __forceinline__ float fast_rcp(float x) {
  float r; asm("v_rcp_f32 %0, %1" : "=v"(r) : "v"(x)); return r;
}

// ---- d_out offsets (float elements), in reference return order ----
#define PATH_OFF   0
#define VARP_OFF   (MC*NGRID)
#define DL_OFF     (2*MC*NGRID)
#define PV_OFF     (2*MC*NGRID + MC)
#define VV_OFF     (PV_OFF + 63)
#define EP_OFF     (VV_OFF + 63)
#define MEAN_OFF   (EP_OFF + MC)
#define VAR_OFF    (MEAN_OFF + 1)
#define ERR_OFF    (VAR_OFF + 1)

// ---- workspace (doubles) ----
#define WS_STRIDE  132
#define MEANE_SLOT (NBLK*WS_STRIDE)

// ---- LDS f32 offsets (dwords) ----
enum : int {
  OFF_DW0 = 0,     // diff Wi t-row, padded 64
  OFF_DW1 = 64,
  OFF_DBI = 128,   // [50]=1.0 (const-1 slot)
  OFF_DWO = 192,
  OFF_VW0 = 256,   // padded 32
  OFF_VW1 = 288,
  OFF_VBI = 320,   // [31]=1.0
  OFF_EBI = 352,   // 32
  OFF_EWO = 384,   // 32
  OFF_SC  = 416,   // [0]=dbo, [1]=ebo  (pad to 420)
  OFF_EWI = 420,   // f32 CURRENT-PERIOD slice [92][20]=1840
  OFF_PSUM= 2260,  // 8 waves * 42 doubles = 672 dw
  OFF_ESUM= 2932,  // 8 waves * 4 doubles = 64 dw
  OFF_DTAB= 2996,  // 91 discounts (+1 pad)
  OFF_PH  = 3088,  // 8 waves * [16][62] f32 path history = 7936 dw
  F16BASE = 11024
};
// ---- f16 offsets (units of f16, relative to smh) ----
enum : int {
  DWH_F  = 0,        // 3 * [64][64] single f16 (bias in k=50; layers 0,1->regs)
  VWH_F  = 12288,    // 2 * [32][40] (bias in k=31)
  EWH_F  = 14848,    // 2 * [32][40] (bias in k=31)
  VWO_F  = 17408,    // [64][40] (bias in k=31; staged -> regs)
  ACT_F  = 19968     // per wave: diff hi [16][72] | diff lo [16][72] | vv | ve
};
#define SMEM_DW   35312
#define SMEM_BYTES (SMEM_DW*4)

__device__ __forceinline__ float softplus_f(float x) {
  return fmaxf(x, 0.0f) + __logf(1.0f + __expf(-fabsf(x)));
}

// ---- diff hidden layer: A in regs (single f16, bias in k=50), B hi/lo LDS ----
__device__ __forceinline__ void mfma_hidden_r(
    const f16x8 (&A)[4][2], f16* acth, f16* actl, int p, int g)
{
  f16x8 Bh[2], Bl[2];
#pragma unroll
  for (int kt = 0; kt < 2; ++kt) {
    const int bi = p*72 + 32*kt + 8*g;
    Bh[kt] = *(const f16x8*)&acth[bi];
    Bl[kt] = *(const f16x8*)&actl[bi];
  }
  f32x4 acc[4];
#pragma unroll
  for (int mt = 0; mt < 4; ++mt) acc[mt] = (f32x4){0.f,0.f,0.f,0.f};
#pragma unroll
  for (int mt = 0; mt < 4; ++mt) {
#pragma unroll
    for (int kt = 0; kt < 2; ++kt) {
      acc[mt] = __builtin_amdgcn_mfma_f32_16x16x32_f16(A[mt][kt], Bl[kt], acc[mt], 0,0,0);
      acc[mt] = __builtin_amdgcn_mfma_f32_16x16x32_f16(A[mt][kt], Bh[kt], acc[mt], 0,0,0);
    }
  }
  CFENCE();
#pragma unroll
  for (int mt = 0; mt < 4; ++mt) {
    f16x4 vh, vl;
#pragma unroll
    for (int r = 0; r < 4; ++r) {
      const float x = fmaxf(acc[mt][r], 0.0f);
      const f16 h = (f16)x;
      vh[r] = h;
      vl[r] = (f16)(x - (float)h);
    }
    const int wi = p*72 + 16*mt + 4*g;
    *(f16x4*)&acth[wi] = vh;
    *(f16x4*)&actl[wi] = vl;
  }
  CFENCE();
}

// ---- same but A fragments read from LDS (layer 2) ----
__device__ __forceinline__ void mfma_hidden_l(
    const f16* __restrict__ Ab, f16* acth, f16* actl, int p, int g)
{
  f16x8 Bh[2], Bl[2];
#pragma unroll
  for (int kt = 0; kt < 2; ++kt) {
    const int bi = p*72 + 32*kt + 8*g;
    Bh[kt] = *(const f16x8*)&acth[bi];
    Bl[kt] = *(const f16x8*)&actl[bi];
  }
  f32x4 acc[4];
#pragma unroll
  for (int mt = 0; mt < 4; ++mt) acc[mt] = (f32x4){0.f,0.f,0.f,0.f};
#pragma unroll
  for (int mt = 0; mt < 4; ++mt) {
#pragma unroll
    for (int kt = 0; kt < 2; ++kt) {
      const f16x8 a = *(const f16x8*)&Ab[(p + 16*mt)*64 + 32*kt + 8*g];
      acc[mt] = __builtin_amdgcn_mfma_f32_16x16x32_f16(a, Bl[kt], acc[mt], 0,0,0);
      acc[mt] = __builtin_amdgcn_mfma_f32_16x16x32_f16(a, Bh[kt], acc[mt], 0,0,0);
    }
  }
  CFENCE();
#pragma unroll
  for (int mt = 0; mt < 4; ++mt) {
    f16x4 vh, vl;
#pragma unroll
    for (int r = 0; r < 4; ++r) {
      const float x = fmaxf(acc[mt][r], 0.0f);
      const f16 h = (f16)x;
      vh[r] = h;
      vl[r] = (f16)(x - (float)h);
    }
    const int wi = p*72 + 16*mt + 4*g;
    *(f16x4*)&acth[wi] = vh;
    *(f16x4*)&actl[wi] = vl;
  }
  CFENCE();
}

__device__ __forceinline__ void diff_L1(const float* sm, f16* acth, f16* actl,
                                        float tp, float Sp, int p, int g)
{
  const int j0 = 16*g;
  f16x8 vh0, vh1, vl0, vl1;
#pragma unroll
  for (int c = 0; c < 4; ++c) {
    const f32x4 w0 = *(const f32x4*)&sm[OFF_DW0 + j0 + 4*c];
    const f32x4 w1 = *(const f32x4*)&sm[OFF_DW1 + j0 + 4*c];
    const f32x4 bi = *(const f32x4*)&sm[OFF_DBI + j0 + 4*c];
#pragma unroll
    for (int r = 0; r < 4; ++r) {
      const float x = fmaxf(fmaf(w0[r], tp, fmaf(w1[r], Sp, bi[r])), 0.0f);
      const f16 h = (f16)x;
      const f16 l = (f16)(x - (float)h);
      if (c < 2) { vh0[c*4+r] = h; vl0[c*4+r] = l; }
      else       { vh1[(c-2)*4+r] = h; vl1[(c-2)*4+r] = l; }
    }
  }
  const int wi0 = p*72 + j0;
  const int wi1 = wi0 + 8;
  *(f16x8*)&acth[wi0] = vh0; *(f16x8*)&acth[wi1] = vh1;
  *(f16x8*)&actl[wi0] = vl0; *(f16x8*)&actl[wi1] = vl1;
  CFENCE();
}

// ---- diff output via row-0 MFMA (A = DWO f16 in regs, dbo at slot 50) ----
__device__ __forceinline__ float diff_out_m(const f16x8 (&oDW)[2],
                                            const f16* acth, const f16* actl,
                                            int p, int g)
{
  f32x4 acc = (f32x4){0.f,0.f,0.f,0.f};
#pragma unroll
  for (int kt = 0; kt < 2; ++kt) {
    const int bi = p*72 + 32*kt + 8*g;
    const f16x8 Bh = *(const f16x8*)&acth[bi];
    const f16x8 Bl = *(const f16x8*)&actl[bi];
    acc = __builtin_amdgcn_mfma_f32_16x16x32_f16(oDW[kt], Bl, acc, 0,0,0);
    acc = __builtin_amdgcn_mfma_f32_16x16x32_f16(oDW[kt], Bh, acc, 0,0,0);
  }
  const float s = __shfl(acc[0], p);   // D[0][p] lives in lane p (g==0)
  return softplus_f(s);
}

// ---- paired small-net hidden layer (A in regs, bias in k=31) ----
__device__ __forceinline__ void small_pair_r(
    const f16x8 (&Av)[2], const f16x8 (&Ae)[2],
    f16* vvact, f16* veact, int p, int g)
{
  const int bi = p*40 + 8*g;
  const f16x8 Bv = *(const f16x8*)&vvact[bi];
  const f16x8 Be = *(const f16x8*)&veact[bi];
  f32x4 av[2], ae[2];
#pragma unroll
  for (int mt = 0; mt < 2; ++mt) {
    av[mt] = __builtin_amdgcn_mfma_f32_16x16x32_f16(Av[mt], Bv,
             (f32x4){0.f,0.f,0.f,0.f}, 0,0,0);
    ae[mt] = __builtin_amdgcn_mfma_f32_16x16x32_f16(Ae[mt], Be,
             (f32x4){0.f,0.f,0.f,0.f}, 0,0,0);
  }
  CFENCE();
#pragma unroll
  for (int mt = 0; mt < 2; ++mt) {
    f16x4 xv, xe;
#pragma unroll
    for (int r = 0; r < 4; ++r) {
      xv[r] = (f16)fmaxf(av[mt][r], 0.0f);
      xe[r] = (f16)fmaxf(ae[mt][r], 0.0f);
    }
    const int wi = p*40 + 16*mt + 4*g;
    *(f16x4*)&vvact[wi] = xv;
    *(f16x4*)&veact[wi] = xe;
  }
  CFENCE();
}

__device__ void load_weights(float* sm, f16* smh, int m, int tid,
  const float* dWi, const float* dbi_g, const float* dWh_g, const float* dbh_g,
  const float* dWo_g, const float* dbo_g,
  const float* vWi, const float* vbi_g, const float* vWh_g, const float* vbh_g,
  const float* vWo_g, const float* vbo_g,
  const float* eWi, const float* ebi_g, const float* eWh_g, const float* ebh_g,
  const float* eWo_g, const float* ebo_g)
{
  for (int j = tid; j < 64; j += TPB) {
    sm[OFF_DW0+j] = (j<50) ? dWi[m*100 + j]      : 0.0f;
    sm[OFF_DW1+j] = (j<50) ? dWi[m*100 + 50 + j] : 0.0f;
    sm[OFF_DBI+j] = (j<50) ? dbi_g[m*50 + j]     : (j==50 ? 1.0f : 0.0f);
    sm[OFF_DWO+j] = (j<50) ? dWo_g[m*50 + j]     : 0.0f;
  }
  for (int j = tid; j < 32; j += TPB) {
    sm[OFF_VW0+j] = (j<30) ? vWi[m*60 + j]      : 0.0f;
    sm[OFF_VW1+j] = (j<30) ? vWi[m*60 + 30 + j] : 0.0f;
    sm[OFF_VBI+j] = (j<30) ? vbi_g[m*30 + j]    : (j==31 ? 1.0f : 0.0f);
    sm[OFF_EBI+j] = (j<20) ? ebi_g[m*20 + j]    : 0.0f;
    sm[OFF_EWO+j] = (j<20) ? eWo_g[m*20 + j]    : 0.0f;
  }
  if (tid == 0) { sm[OFF_SC] = dbo_g[m]; sm[OFF_SC+1] = ebo_g[m]; }

  // EWI slice for period m ([92][20])
  for (int idx = tid; idx < 1840; idx += TPB)
    sm[OFF_EWI + idx] = eWi[m*1840 + idx];

  // diff hidden weights -> single f16, A[j][k] = W[k][j]; bias in k=50;
  // const-1 self-sustain A[50][50]=1
  for (int idx = tid; idx < 12288; idx += TPB) {
    const int l = idx >> 12, j = (idx >> 6) & 63, k = idx & 63;
    float w = 0.0f;
    if (j < 50 && k < 50)      w = dWh_g[((m*3+l)*50 + k)*50 + j];
    else if (k == 50 && j < 50) w = dbh_g[(m*3+l)*50 + j];
    else if (k == 50 && j == 50) w = 1.0f;
    smh[DWH_F + idx] = (f16)w;
  }
  // vv & ve hidden: A[j][k] single f16, [32][40]; bias in k=31; A[31][31]=1
  for (int idx = tid; idx < 2560; idx += TPB) {
    const int l = idx / 1280, r = idx % 1280, j = r / 40, k = r % 40;
    float wv = 0.0f, we = 0.0f;
    if (j < 30 && k < 30)       wv = vWh_g[((m*2+l)*30 + k)*30 + j];
    else if (k == 31 && j < 30)  wv = vbh_g[(m*2+l)*30 + j];
    else if (k == 31 && j == 31) wv = 1.0f;
    if (j < 20 && k < 20)       we = eWh_g[((m*2+l)*20 + k)*20 + j];
    else if (k == 31 && j < 20)  we = ebh_g[(m*2+l)*20 + j];
    else if (k == 31 && j == 31) we = 1.0f;
    smh[VWH_F + idx] = (f16)wv;
    smh[EWH_F + idx] = (f16)we;
  }
  // vOut: A[s][k] = vWo[k][s], [64][40]; bias in k=31
  for (int idx = tid; idx < 2560; idx += TPB) {
    const int s = idx / 40, k = idx % 40;
    float w = 0.0f;
    if (s < 63 && k < 30)       w = vWo_g[(m*30 + k)*63 + s];
    else if (s < 63 && k == 31) w = vbo_g[m*63 + s];
    smh[VWO_F + idx] = (f16)w;
  }
}

extern "C" __global__ void __launch_bounds__(TPB)
__attribute__((amdgpu_waves_per_eu(2, 2)))
sim_kernel(const float* __restrict__ S0g, const float* __restrict__ zg,
           const float* dWi, const float* dbi_g, const float* dWh_g,
           const float* dbh_g, const float* dWo_g, const float* dbo_g,
           const float* vWi, const float* vbi_g, const float* vWh_g,
           const float* vbh_g, const float* vWo_g, const float* vbo_g,
           const float* eWi, const float* ebi_g, const float* eWh_g,
           const float* ebh_g, const float* eWo_g, const float* ebo_g,
           float* __restrict__ out, double* __restrict__ wsd)
{
  extern __shared__ float sm[];
  f16* smh = (f16*)&sm[F16BASE];
  const int tid  = threadIdx.x;
  const int wv   = tid >> 6;          // wave 0..7, owns 16 paths
  const int lane = tid & 63;
  const int p    = lane & 15;
  const int g    = lane >> 4;
  f16* acth  = smh + ACT_F + wv*3584; // [16][72]
  f16* actl  = acth + 1152;
  f16* vvact = acth + 2304;           // [16][40]
  f16* veact = acth + 2944;           // [16][40]
  float* ph  = sm + OFF_PH + wv*992;  // [16][62]
  const int P0 = blockIdx.x*128 + wv*16;
  const float S0v = S0g[0];

  for (int j = tid; j < 91; j += TPB)
    sm[OFF_DTAB + j] = expf(-RATEf * (0.01f * (float)j));

  f32x4 cvv[4];
#pragma unroll
  for (int mt = 0; mt < 4; ++mt) cvv[mt] = (f32x4){0.f,0.f,0.f,0.f};
  float S = S0v, rmax = S0v, cve = 0.0f;
  float accCur[8];

  if (g == 0) out[PATH_OFF + (size_t)(P0 + p) * NGRID + 0] = S0v;

  for (int m = 0; m < 3; ++m) {
    __syncthreads();
    load_weights(sm, smh, m, tid, dWi, dbi_g, dWh_g, dbh_g, dWo_g, dbo_g,
                 vWi, vbi_g, vWh_g, vbh_g, vWo_g, vbo_g,
                 eWi, ebi_g, eWh_g, ebh_g, eWo_g, ebo_g);
    __syncthreads();

    // ---- period-invariant A fragments -> registers ----
    f16x8 dA[2][4][2];   // diff layers 0,1 (layer 2 from LDS)
#pragma unroll
    for (int l = 0; l < 2; ++l)
#pragma unroll
      for (int mt = 0; mt < 4; ++mt)
#pragma unroll
        for (int kt = 0; kt < 2; ++kt)
          dA[l][mt][kt] = *(const f16x8*)
              &smh[DWH_F + l*4096 + (p + 16*mt)*64 + 32*kt + 8*g];
    f16x8 vA1[2], vA2[2], eA1[2], eA2[2], oA[4];
#pragma unroll
    for (int mt = 0; mt < 2; ++mt) {
      vA1[mt] = *(const f16x8*)&smh[VWH_F +        (p + 16*mt)*40 + 8*g];
      vA2[mt] = *(const f16x8*)&smh[VWH_F + 1280 + (p + 16*mt)*40 + 8*g];
      eA1[mt] = *(const f16x8*)&smh[EWH_F +        (p + 16*mt)*40 + 8*g];
      eA2[mt] = *(const f16x8*)&smh[EWH_F + 1280 + (p + 16*mt)*40 + 8*g];
    }
#pragma unroll
    for (int mt = 0; mt < 4; ++mt)
      oA[mt] = *(const f16x8*)&smh[VWO_F + (p + 16*mt)*40 + 8*g];

    // output-layer A fragments (row 0 = weights; dbo/ebo in bias slot)
    f16x8 oDW[2], oEW;
#pragma unroll
    for (int kt = 0; kt < 2; ++kt)
#pragma unroll
      for (int e = 0; e < 8; ++e) {
        const int k = 32*kt + 8*g + e;
        float v = 0.0f;
        if (p == 0) v = (k < 50) ? sm[OFF_DWO + k]
                                 : (k == 50 ? sm[OFF_SC] : 0.0f);
        oDW[kt][e] = (f16)v;
      }
#pragma unroll
    for (int e = 0; e < 8; ++e) {
      const int k = 8*g + e;
      float v = 0.0f;
      if (p == 0) v = (k < 20) ? sm[OFF_EWO + k]
                               : (k == 31 ? sm[OFF_SC + 1] : 0.0f);
      oEW[e] = (f16)v;
    }

    // accCur for period m (m=0: from S0; m>0: recompute from path history,
    // bit-identical k-order)
#pragma unroll
    for (int e = 0; e < 8; ++e)
      accCur[e] = S0v * sm[OFF_EWI + 20 + 8*g + e];
    const int kmax = 30*m;
    for (int k = 1; k <= kmax; ++k) {
      const float Sk = ph[p*62 + k];
      const int ro = (1 + k)*20 + 8*g;
      const f32x4 w0 = *(const f32x4*)&sm[OFF_EWI + ro];
      const f32x4 w1 = *(const f32x4*)&sm[OFF_EWI + ro + 4];
#pragma unroll
      for (int e = 0; e < 4; ++e) {
        accCur[e]   = fmaf(Sk, w0[e], accCur[e]);
        accCur[e+4] = fmaf(Sk, w1[e], accCur[e+4]);
      }
    }

    if (m == 0) {
      diff_L1(sm, acth, actl, 0.0f, S, p, g);
      mfma_hidden_r(dA[0], acth, actl, p, g);
      mfma_hidden_r(dA[1], acth, actl, p, g);
      mfma_hidden_l(smh + DWH_F + 8192, acth, actl, p, g);
      const float d0 = diff_out_m(oDW, acth, actl, p, g);
      if (g == 0)
        out[VARP_OFF + (size_t)(P0 + p) * NGRID + 0] = d0 * d0;
      CFENCE();
    }

    for (int it = 1; it <= 30; ++it) {
      const int i = m*30 + it;
      const float ti = 0.01f * (float)i;
      const float tp = 0.01f * (float)(i - 1);
      const float hstep = ti - tp;
      const float sqh = sqrtf(hstep);
      const float disc = sm[OFF_DTAB + (i - 1)];
      const float zval = zg[(size_t)(P0 + p) * NSTEPS + (i - 1)];
      const float dWv = sqh * zval;

      // ---------------- small-net L1s ----------------
      { // vL1: rows 8g..8g+7 (row 31 -> 1.0 via VBI[31])
        const int j0 = 8*g;
        f16x8 vh;
#pragma unroll
        for (int c = 0; c < 2; ++c) {
          const f32x4 w0 = *(const f32x4*)&sm[OFF_VW0 + j0 + 4*c];
          const f32x4 w1 = *(const f32x4*)&sm[OFF_VW1 + j0 + 4*c];
          const f32x4 bi = *(const f32x4*)&sm[OFF_VBI + j0 + 4*c];
#pragma unroll
          for (int r = 0; r < 4; ++r)
            vh[c*4+r] = (f16)fmaxf(fmaf(w0[r], tp, fmaf(w1[r], S, bi[r])), 0.0f);
        }
        *(f16x8*)&vvact[p*40 + j0] = vh;
      }
      { // eL1: rows 8g..8g+7; row 31 forced to 1.0 (const slot)
        const int j0 = 8*g;
        const f32x4 t0 = *(const f32x4*)&sm[OFF_EWI + j0];
        const f32x4 t1 = *(const f32x4*)&sm[OFF_EWI + j0 + 4];
        const f32x4 b0 = *(const f32x4*)&sm[OFF_EBI + j0];
        const f32x4 b1 = *(const f32x4*)&sm[OFF_EBI + j0 + 4];
        f16x8 vh;
#pragma unroll
        for (int e = 0; e < 8; ++e) {
          const float wt = (e < 4) ? t0[e] : t1[e-4];
          const float bb = (e < 4) ? b0[e] : b1[e-4];
          float x = fmaxf(fmaf(wt, tp, accCur[e] + bb), 0.0f);
          if (j0 + e == 31) x = 1.0f;
          vh[e] = (f16)x;
        }
        *(f16x8*)&veact[p*40 + j0] = vh;
      }
      CFENCE();
      small_pair_r(vA1, eA1, vvact, veact, p, g);
      small_pair_r(vA2, eA2, vvact, veact, p, g);

      // ---------------- diff net ----------------
      diff_L1(sm, acth, actl, tp, S, p, g);
      mfma_hidden_r(dA[0], acth, actl, p, g);
      mfma_hidden_r(dA[1], acth, actl, p, g);
      mfma_hidden_l(smh + DWH_F + 8192, acth, actl, p, g);
      const float d = diff_out_m(oDW, acth, actl, p, g);
      const float gg = ((disc * S) * d) * dWv;   // S is old S
      if (g == 0) {
        out[VARP_OFF + (size_t)(P0 + p) * NGRID + i] = d * d;
        if (i == NSTEPS) out[DL_OFF + (P0 + p)] = d;
      }

      // ---------------- vOut (bias in A slot 31) + cvv ----------------
      {
        const f16x8 Bv = *(const f16x8*)&vvact[p*40 + 8*g];
#pragma unroll
        for (int mt = 0; mt < 4; ++mt) {
          const f32x4 acc = __builtin_amdgcn_mfma_f32_16x16x32_f16(
              oA[mt], Bv, (f32x4){0.f,0.f,0.f,0.f}, 0,0,0);
#pragma unroll
          for (int r = 0; r < 4; ++r)
            cvv[mt][r] = fmaf(gg, acc[r], cvv[mt][r]);
        }
      }
      // ---------------- eOut via row-0 MFMA ----------------
      {
        const f16x8 Be = *(const f16x8*)&veact[p*40 + 8*g];
        const f32x4 acc = __builtin_amdgcn_mfma_f32_16x16x32_f16(
            oEW, Be, (f32x4){0.f,0.f,0.f,0.f}, 0,0,0);
        const float eouts = __shfl(acc[0], p);
        cve = fmaf(gg, eouts, cve);
      }

      // ---------------- state update ----------------
      const float Sold = S;
      const float t1_ = (RATEf*Sold*hstep) * fast_rcp(1.0f + (RATEf*Sold)*sqh);
      const float t2_ = ((Sold*d)*dWv)     * fast_rcp(1.0f + (Sold*d)*sqh);
      const float Snew = (Sold + t1_) + t2_;
      S = Snew;
      rmax = fmaxf(rmax, Snew);
      if (g == 0) {
        out[PATH_OFF + (size_t)(P0 + p) * NGRID + i] = Snew;
        if (i <= 60) ph[p*62 + i] = Snew;
      }
      { // incremental cve-L1 update, EWI row (1+i)
        const int ro = OFF_EWI + (1 + i)*20 + 8*g;
        const f32x4 a0 = *(const f32x4*)&sm[ro];
        const f32x4 a1 = *(const f32x4*)&sm[ro + 4];
#pragma unroll
        for (int e = 0; e < 4; ++e) {
          accCur[e]   = fmaf(Snew, a0[e], accCur[e]);
          accCur[e+4] = fmaf(Snew, a1[e], accCur[e+4]);
        }
      }
      CFENCE();
    } // steps

    // ---------------- period-end price partials ----------------
    {
      const float discm = sm[OFF_DTAB + 30*(m+1)];
      double* ps = (double*)&sm[OFF_PSUM];
#pragma unroll
      for (int mt = 0; mt < 4; ++mt) {
#pragma unroll
        for (int r = 0; r < 4; ++r) {
          const int s = 16*mt + 4*g + r;
          const bool act = (s >= 21*m) && (s < 21*m + 21);
          double s1 = 0.0, s2 = 0.0;
          if (act) {
            const float Kst = 0.8f + 0.02f * (float)(s - 21*m);
            const float pr_ = discm * fmaxf(S - Kst, 0.0f) - cvv[mt][r];
            s1 = (double)pr_;
            s2 = (double)pr_ * (double)pr_;
          }
          s1 += __shfl_xor(s1, 1); s1 += __shfl_xor(s1, 2);
          s1 += __shfl_xor(s1, 4); s1 += __shfl_xor(s1, 8);
          s2 += __shfl_xor(s2, 1); s2 += __shfl_xor(s2, 2);
          s2 += __shfl_xor(s2, 4); s2 += __shfl_xor(s2, 8);
          if (act && p == 0) {
            const int sI = s - 21*m;
            ps[wv*42 + sI*2 + 0] = s1;
            ps[wv*42 + sI*2 + 1] = s2;
          }
        }
      }
    }
    __syncthreads();
    if (tid < 21) {
      double* ps = (double*)&sm[OFF_PSUM];
      double a = 0.0, b = 0.0;
      for (int w = 0; w < 8; ++w) { a += ps[w*42 + tid*2]; b += ps[w*42 + tid*2 + 1]; }
      wsd[(size_t)blockIdx.x*WS_STRIDE + (m*21+tid)*2 + 0] = a;
      wsd[(size_t)blockIdx.x*WS_STRIDE + (m*21+tid)*2 + 1] = b;
    }
  } // periods

  // ---------------- exotic outputs & partials ----------------
  const float discT = sm[OFF_DTAB + 90];
  const float e  = discT * (rmax - S);
  const float ep = e - cve;
  if (g == 0) out[EP_OFF + (P0 + p)] = ep;
  double de  = (g == 0) ? (double)e  : 0.0;
  double dp  = (g == 0) ? (double)ep : 0.0;
  double dp2 = (g == 0) ? (double)ep * (double)ep : 0.0;
#pragma unroll
  for (int msk = 1; msk <= 32; msk <<= 1) {
    de  += __shfl_xor(de,  msk);
    dp  += __shfl_xor(dp,  msk);
    dp2 += __shfl_xor(dp2, msk);
  }
  {
    double* es = (double*)&sm[OFF_ESUM];
    if (lane == 0) { es[wv*4+0] = de; es[wv*4+1] = dp; es[wv*4+2] = dp2; }
  }
  __syncthreads();
  if (tid == 0) {
    double* es = (double*)&sm[OFF_ESUM];
    double a = 0, b = 0, c = 0;
    for (int w = 0; w < 8; ++w) { a += es[w*4]; b += es[w*4+1]; c += es[w*4+2]; }
    wsd[(size_t)blockIdx.x*WS_STRIDE + 126] = a;
    wsd[(size_t)blockIdx.x*WS_STRIDE + 127] = b;
    wsd[(size_t)blockIdx.x*WS_STRIDE + 128] = c;
  }
}

extern "C" __global__ void finalize_kernel(double* __restrict__ wsd,
                                           float* __restrict__ out)
{
  const int t = threadIdx.x;
  if (t < 63) {
    double a = 0.0, b = 0.0;
    for (int blk = 0; blk < NBLK; ++blk) {
      a += wsd[(size_t)blk*WS_STRIDE + t*2 + 0];
      b += wsd[(size_t)blk*WS_STRIDE + t*2 + 1];
    }
    const double mean = a / (double)MC;
    const double var  = (b - a*a/(double)MC) / (double)(MC - 1);
    out[PV_OFF + t] = (float)mean;
    out[VV_OFF + t] = (float)var;
  } else if (t == 64) {
    double a = 0.0;
    for (int blk = 0; blk < NBLK; ++blk) a += wsd[(size_t)blk*WS_STRIDE + 126];
    wsd[MEANE_SLOT] = a / (double)MC;
  } else if (t == 65) {
    double a = 0.0, c = 0.0;
    for (int blk = 0; blk < NBLK; ++blk) {
      a += wsd[(size_t)blk*WS_STRIDE + 127];
      c += wsd[(size_t)blk*WS_STRIDE + 128];
    }
    out[MEAN_OFF] = (float)(a / (double)MC);
    out[VAR_OFF]  = (float)((c - a*a/(double)MC) / (double)(MC - 1));
  }
}

extern "C" __global__ void error_kernel(const double* __restrict__ wsd,
                                        float* __restrict__ out)
{
  const int pth = blockIdx.x * 256 + threadIdx.x;
  if (pth < MC) {
    const float meanE = (float)wsd[MEANE_SLOT];
    out[ERR_OFF + pth] = out[EP_OFF + pth] - meanE;
  }
}

extern "C" void kernel_launch(void* const* d_in, const int* in_sizes, int n_in,
                              void* d_out, int out_size, void* d_ws, size_t ws_size,
                              hipStream_t stream)
{
  (void)in_sizes; (void)n_in; (void)out_size; (void)ws_size;
  const float* S0g  = (const float*)d_in[0];
  const float* zg   = (const float*)d_in[1];
  // d_in[2..4] = MC_samples / ind_T / period_length (fixed constants)
  const float* dWi  = (const float*)d_in[5];
  const float* dbi  = (const float*)d_in[6];
  const float* dWh  = (const float*)d_in[7];
  const float* dbh  = (const float*)d_in[8];
  const float* dWo  = (const float*)d_in[9];
  const float* dbo  = (const float*)d_in[10];
  const float* vWi  = (const float*)d_in[11];
  const float* vbi  = (const float*)d_in[12];
  const float* vWh  = (const float*)d_in[13];
  const float* vbh  = (const float*)d_in[14];
  const float* vWo  = (const float*)d_in[15];
  const float* vbo  = (const float*)d_in[16];
  const float* eWi  = (const float*)d_in[17];
  const float* ebi  = (const float*)d_in[18];
  const float* eWh  = (const float*)d_in[19];
  const float* ebh  = (const float*)d_in[20];
  const float* eWo  = (const float*)d_in[21];
  const float* ebo  = (const float*)d_in[22];
  float* out  = (float*)d_out;
  double* wsd = (double*)d_ws;

  hipFuncSetAttribute(reinterpret_cast<const void*>(sim_kernel),
                      hipFuncAttributeMaxDynamicSharedMemorySize, SMEM_BYTES);

  sim_kernel<<<NBLK, TPB, SMEM_BYTES, stream>>>(
      S0g, zg, dWi, dbi, dWh, dbh, dWo, dbo,
      vWi, vbi, vWh, vbh, vWo, vbo,
      eWi, ebi, eWh, ebh, eWo, ebo, out, wsd);
  finalize_kernel<<<1, 128, 0, stream>>>(wsd, out);
  error_kernel<<<MC/256, 256, 0, stream>>>(wsd, out);
}

// Round 17
// 347.374 us; speedup vs baseline: 1.5751x; 1.2492x over previous
//
#include <hip/hip_runtime.h>
#include <math.h>

// ---------------------------------------------------------------------------
// Net_LV Monte-Carlo local-vol simulation, MI355X (gfx950)  — MFMA version 12
// 256 blocks x 512 threads (8 independent waves x 16 paths, no step-loop
// barriers). v12 = v11 with SINGLE-f16 activations in the diff chain (the
// B lo-term dropped): halves diff MFMAs, removes ~25% of DS traffic and the
// per-layer hi/lo re-split VALU. A single-f16 in regs (layers 0,1) / LDS
// (layer 2); biases folded into A via const-1.0 k-slots; output dots as
// row-0 MFMAs.
// ---------------------------------------------------------------------------

#define TPB 512
#define NBLK 256
#define MC 32768
#define NSTEPS 90
#define NGRID 91
#define RATEf 0.025f

typedef _Float16 f16;
typedef f16 f16x8 __attribute__((ext_vector_type(8)));
typedef f16 f16x4 __attribute__((ext_vector_type(4)));
typedef float f32x4 __attribute__((ext_vector_type(4)));

#define CFENCE() asm volatile("" ::: "memory")

__device__ __forceinline__ float fast_rcp(float x) {
  float r; asm("v_rcp_f32 %0, %1" : "=v"(r) : "v"(x)); return r;
}

// ---- d_out offsets (float elements), in reference return order ----
#define PATH_OFF   0
#define VARP_OFF   (MC*NGRID)
#define DL_OFF     (2*MC*NGRID)
#define PV_OFF     (2*MC*NGRID + MC)
#define VV_OFF     (PV_OFF + 63)
#define EP_OFF     (VV_OFF + 63)
#define MEAN_OFF   (EP_OFF + MC)
#define VAR_OFF    (MEAN_OFF + 1)
#define ERR_OFF    (VAR_OFF + 1)

// ---- workspace (doubles) ----
#define WS_STRIDE  132
#define MEANE_SLOT (NBLK*WS_STRIDE)

// ---- LDS f32 offsets (dwords) ----
enum : int {
  OFF_DW0 = 0,     // diff Wi t-row, padded 64
  OFF_DW1 = 64,
  OFF_DBI = 128,   // [50]=1.0 (const-1 slot)
  OFF_DWO = 192,
  OFF_VW0 = 256,   // padded 32
  OFF_VW1 = 288,
  OFF_VBI = 320,   // [31]=1.0
  OFF_EBI = 352,   // 32
  OFF_EWO = 384,   // 32
  OFF_SC  = 416,   // [0]=dbo, [1]=ebo  (pad to 420)
  OFF_EWI = 420,   // f32 CURRENT-PERIOD slice [92][20]=1840
  OFF_PSUM= 2260,  // 8 waves * 42 doubles = 672 dw
  OFF_ESUM= 2932,  // 8 waves * 4 doubles = 64 dw
  OFF_DTAB= 2996,  // 91 discounts (+1 pad)
  OFF_PH  = 3088,  // 8 waves * [16][62] f32 path history = 7936 dw
  F16BASE = 11024
};
// ---- f16 offsets (units of f16, relative to smh) ----
enum : int {
  DWH_F  = 0,        // 3 * [64][64] single f16 (bias in k=50; layers 0,1->regs)
  VWH_F  = 12288,    // 2 * [32][40] (bias in k=31)
  EWH_F  = 14848,    // 2 * [32][40] (bias in k=31)
  VWO_F  = 17408,    // [64][40] (bias in k=31; staged -> regs)
  ACT_F  = 19968     // per wave: diff [16][72] | vv [16][40] | ve [16][40]
};
#define SMEM_DW   30736
#define SMEM_BYTES (SMEM_DW*4)

__device__ __forceinline__ float softplus_f(float x) {
  return fmaxf(x, 0.0f) + __logf(1.0f + __expf(-fabsf(x)));
}

// ---- diff hidden layer: A in regs (single f16, bias in k=50), B f16 LDS ----
__device__ __forceinline__ void mfma_hidden_r(
    const f16x8 (&A)[4][2], f16* acth, int p, int g)
{
  f16x8 Bh[2];
#pragma unroll
  for (int kt = 0; kt < 2; ++kt)
    Bh[kt] = *(const f16x8*)&acth[p*72 + 32*kt + 8*g];
  f32x4 acc[4];
#pragma unroll
  for (int mt = 0; mt < 4; ++mt) acc[mt] = (f32x4){0.f,0.f,0.f,0.f};
#pragma unroll
  for (int mt = 0; mt < 4; ++mt)
#pragma unroll
    for (int kt = 0; kt < 2; ++kt)
      acc[mt] = __builtin_amdgcn_mfma_f32_16x16x32_f16(A[mt][kt], Bh[kt], acc[mt], 0,0,0);
  CFENCE();
#pragma unroll
  for (int mt = 0; mt < 4; ++mt) {
    f16x4 vh;
#pragma unroll
    for (int r = 0; r < 4; ++r)
      vh[r] = (f16)fmaxf(acc[mt][r], 0.0f);
    *(f16x4*)&acth[p*72 + 16*mt + 4*g] = vh;
  }
  CFENCE();
}

// ---- same but A fragments read from LDS (layer 2) ----
__device__ __forceinline__ void mfma_hidden_l(
    const f16* __restrict__ Ab, f16* acth, int p, int g)
{
  f16x8 Bh[2];
#pragma unroll
  for (int kt = 0; kt < 2; ++kt)
    Bh[kt] = *(const f16x8*)&acth[p*72 + 32*kt + 8*g];
  f32x4 acc[4];
#pragma unroll
  for (int mt = 0; mt < 4; ++mt) acc[mt] = (f32x4){0.f,0.f,0.f,0.f};
#pragma unroll
  for (int mt = 0; mt < 4; ++mt)
#pragma unroll
    for (int kt = 0; kt < 2; ++kt) {
      const f16x8 a = *(const f16x8*)&Ab[(p + 16*mt)*64 + 32*kt + 8*g];
      acc[mt] = __builtin_amdgcn_mfma_f32_16x16x32_f16(a, Bh[kt], acc[mt], 0,0,0);
    }
  CFENCE();
#pragma unroll
  for (int mt = 0; mt < 4; ++mt) {
    f16x4 vh;
#pragma unroll
    for (int r = 0; r < 4; ++r)
      vh[r] = (f16)fmaxf(acc[mt][r], 0.0f);
    *(f16x4*)&acth[p*72 + 16*mt + 4*g] = vh;
  }
  CFENCE();
}

__device__ __forceinline__ void diff_L1(const float* sm, f16* acth,
                                        float tp, float Sp, int p, int g)
{
  const int j0 = 16*g;
  f16x8 vh0, vh1;
#pragma unroll
  for (int c = 0; c < 4; ++c) {
    const f32x4 w0 = *(const f32x4*)&sm[OFF_DW0 + j0 + 4*c];
    const f32x4 w1 = *(const f32x4*)&sm[OFF_DW1 + j0 + 4*c];
    const f32x4 bi = *(const f32x4*)&sm[OFF_DBI + j0 + 4*c];
#pragma unroll
    for (int r = 0; r < 4; ++r) {
      const f16 h = (f16)fmaxf(fmaf(w0[r], tp, fmaf(w1[r], Sp, bi[r])), 0.0f);
      if (c < 2) vh0[c*4+r] = h;
      else       vh1[(c-2)*4+r] = h;
    }
  }
  *(f16x8*)&acth[p*72 + j0]     = vh0;
  *(f16x8*)&acth[p*72 + j0 + 8] = vh1;
  CFENCE();
}

// ---- diff output via row-0 MFMA (A = DWO f16 in regs, dbo at slot 50) ----
__device__ __forceinline__ float diff_out_m(const f16x8 (&oDW)[2],
                                            const f16* acth, int p, int g)
{
  f32x4 acc = (f32x4){0.f,0.f,0.f,0.f};
#pragma unroll
  for (int kt = 0; kt < 2; ++kt) {
    const f16x8 Bh = *(const f16x8*)&acth[p*72 + 32*kt + 8*g];
    acc = __builtin_amdgcn_mfma_f32_16x16x32_f16(oDW[kt], Bh, acc, 0,0,0);
  }
  const float s = __shfl(acc[0], p);   // D[0][p] lives in lane p (g==0)
  return softplus_f(s);
}

// ---- paired small-net hidden layer (A in regs, bias in k=31) ----
__device__ __forceinline__ void small_pair_r(
    const f16x8 (&Av)[2], const f16x8 (&Ae)[2],
    f16* vvact, f16* veact, int p, int g)
{
  const int bi = p*40 + 8*g;
  const f16x8 Bv = *(const f16x8*)&vvact[bi];
  const f16x8 Be = *(const f16x8*)&veact[bi];
  f32x4 av[2], ae[2];
#pragma unroll
  for (int mt = 0; mt < 2; ++mt) {
    av[mt] = __builtin_amdgcn_mfma_f32_16x16x32_f16(Av[mt], Bv,
             (f32x4){0.f,0.f,0.f,0.f}, 0,0,0);
    ae[mt] = __builtin_amdgcn_mfma_f32_16x16x32_f16(Ae[mt], Be,
             (f32x4){0.f,0.f,0.f,0.f}, 0,0,0);
  }
  CFENCE();
#pragma unroll
  for (int mt = 0; mt < 2; ++mt) {
    f16x4 xv, xe;
#pragma unroll
    for (int r = 0; r < 4; ++r) {
      xv[r] = (f16)fmaxf(av[mt][r], 0.0f);
      xe[r] = (f16)fmaxf(ae[mt][r], 0.0f);
    }
    const int wi = p*40 + 16*mt + 4*g;
    *(f16x4*)&vvact[wi] = xv;
    *(f16x4*)&veact[wi] = xe;
  }
  CFENCE();
}

__device__ void load_weights(float* sm, f16* smh, int m, int tid,
  const float* dWi, const float* dbi_g, const float* dWh_g, const float* dbh_g,
  const float* dWo_g, const float* dbo_g,
  const float* vWi, const float* vbi_g, const float* vWh_g, const float* vbh_g,
  const float* vWo_g, const float* vbo_g,
  const float* eWi, const float* ebi_g, const float* eWh_g, const float* ebh_g,
  const float* eWo_g, const float* ebo_g)
{
  for (int j = tid; j < 64; j += TPB) {
    sm[OFF_DW0+j] = (j<50) ? dWi[m*100 + j]      : 0.0f;
    sm[OFF_DW1+j] = (j<50) ? dWi[m*100 + 50 + j] : 0.0f;
    sm[OFF_DBI+j] = (j<50) ? dbi_g[m*50 + j]     : (j==50 ? 1.0f : 0.0f);
    sm[OFF_DWO+j] = (j<50) ? dWo_g[m*50 + j]     : 0.0f;
  }
  for (int j = tid; j < 32; j += TPB) {
    sm[OFF_VW0+j] = (j<30) ? vWi[m*60 + j]      : 0.0f;
    sm[OFF_VW1+j] = (j<30) ? vWi[m*60 + 30 + j] : 0.0f;
    sm[OFF_VBI+j] = (j<30) ? vbi_g[m*30 + j]    : (j==31 ? 1.0f : 0.0f);
    sm[OFF_EBI+j] = (j<20) ? ebi_g[m*20 + j]    : 0.0f;
    sm[OFF_EWO+j] = (j<20) ? eWo_g[m*20 + j]    : 0.0f;
  }
  if (tid == 0) { sm[OFF_SC] = dbo_g[m]; sm[OFF_SC+1] = ebo_g[m]; }

  // EWI slice for period m ([92][20])
  for (int idx = tid; idx < 1840; idx += TPB)
    sm[OFF_EWI + idx] = eWi[m*1840 + idx];

  // diff hidden weights -> single f16, A[j][k] = W[k][j]; bias in k=50;
  // const-1 self-sustain A[50][50]=1
  for (int idx = tid; idx < 12288; idx += TPB) {
    const int l = idx >> 12, j = (idx >> 6) & 63, k = idx & 63;
    float w = 0.0f;
    if (j < 50 && k < 50)      w = dWh_g[((m*3+l)*50 + k)*50 + j];
    else if (k == 50 && j < 50) w = dbh_g[(m*3+l)*50 + j];
    else if (k == 50 && j == 50) w = 1.0f;
    smh[DWH_F + idx] = (f16)w;
  }
  // vv & ve hidden: A[j][k] single f16, [32][40]; bias in k=31; A[31][31]=1
  for (int idx = tid; idx < 2560; idx += TPB) {
    const int l = idx / 1280, r = idx % 1280, j = r / 40, k = r % 40;
    float wv = 0.0f, we = 0.0f;
    if (j < 30 && k < 30)       wv = vWh_g[((m*2+l)*30 + k)*30 + j];
    else if (k == 31 && j < 30)  wv = vbh_g[(m*2+l)*30 + j];
    else if (k == 31 && j == 31) wv = 1.0f;
    if (j < 20 && k < 20)       we = eWh_g[((m*2+l)*20 + k)*20 + j];
    else if (k == 31 && j < 20)  we = ebh_g[(m*2+l)*20 + j];
    else if (k == 31 && j == 31) we = 1.0f;
    smh[VWH_F + idx] = (f16)wv;
    smh[EWH_F + idx] = (f16)we;
  }
  // vOut: A[s][k] = vWo[k][s], [64][40]; bias in k=31
  for (int idx = tid; idx < 2560; idx += TPB) {
    const int s = idx / 40, k = idx % 40;
    float w = 0.0f;
    if (s < 63 && k < 30)       w = vWo_g[(m*30 + k)*63 + s];
    else if (s < 63 && k == 31) w = vbo_g[m*63 + s];
    smh[VWO_F + idx] = (f16)w;
  }
}

extern "C" __global__ void __launch_bounds__(TPB)
__attribute__((amdgpu_waves_per_eu(2, 2)))
sim_kernel(const float* __restrict__ S0g, const float* __restrict__ zg,
           const float* dWi, const float* dbi_g, const float* dWh_g,
           const float* dbh_g, const float* dWo_g, const float* dbo_g,
           const float* vWi, const float* vbi_g, const float* vWh_g,
           const float* vbh_g, const float* vWo_g, const float* vbo_g,
           const float* eWi, const float* ebi_g, const float* eWh_g,
           const float* ebh_g, const float* eWo_g, const float* ebo_g,
           float* __restrict__ out, double* __restrict__ wsd)
{
  extern __shared__ float sm[];
  f16* smh = (f16*)&sm[F16BASE];
  const int tid  = threadIdx.x;
  const int wv   = tid >> 6;          // wave 0..7, owns 16 paths
  const int lane = tid & 63;
  const int p    = lane & 15;
  const int g    = lane >> 4;
  f16* acth  = smh + ACT_F + wv*2432; // [16][72]
  f16* vvact = acth + 1152;           // [16][40]
  f16* veact = acth + 1792;           // [16][40]
  float* ph  = sm + OFF_PH + wv*992;  // [16][62]
  const int P0 = blockIdx.x*128 + wv*16;
  const float S0v = S0g[0];

  for (int j = tid; j < 91; j += TPB)
    sm[OFF_DTAB + j] = expf(-RATEf * (0.01f * (float)j));

  f32x4 cvv[4];
#pragma unroll
  for (int mt = 0; mt < 4; ++mt) cvv[mt] = (f32x4){0.f,0.f,0.f,0.f};
  float S = S0v, rmax = S0v, cve = 0.0f;
  float accCur[8];

  if (g == 0) out[PATH_OFF + (size_t)(P0 + p) * NGRID + 0] = S0v;

  for (int m = 0; m < 3; ++m) {
    __syncthreads();
    load_weights(sm, smh, m, tid, dWi, dbi_g, dWh_g, dbh_g, dWo_g, dbo_g,
                 vWi, vbi_g, vWh_g, vbh_g, vWo_g, vbo_g,
                 eWi, ebi_g, eWh_g, ebh_g, eWo_g, ebo_g);
    __syncthreads();

    // ---- period-invariant A fragments -> registers ----
    f16x8 dA[2][4][2];   // diff layers 0,1 (layer 2 from LDS)
#pragma unroll
    for (int l = 0; l < 2; ++l)
#pragma unroll
      for (int mt = 0; mt < 4; ++mt)
#pragma unroll
        for (int kt = 0; kt < 2; ++kt)
          dA[l][mt][kt] = *(const f16x8*)
              &smh[DWH_F + l*4096 + (p + 16*mt)*64 + 32*kt + 8*g];
    f16x8 vA1[2], vA2[2], eA1[2], eA2[2], oA[4];
#pragma unroll
    for (int mt = 0; mt < 2; ++mt) {
      vA1[mt] = *(const f16x8*)&smh[VWH_F +        (p + 16*mt)*40 + 8*g];
      vA2[mt] = *(const f16x8*)&smh[VWH_F + 1280 + (p + 16*mt)*40 + 8*g];
      eA1[mt] = *(const f16x8*)&smh[EWH_F +        (p + 16*mt)*40 + 8*g];
      eA2[mt] = *(const f16x8*)&smh[EWH_F + 1280 + (p + 16*mt)*40 + 8*g];
    }
#pragma unroll
    for (int mt = 0; mt < 4; ++mt)
      oA[mt] = *(const f16x8*)&smh[VWO_F + (p + 16*mt)*40 + 8*g];

    // output-layer A fragments (row 0 = weights; dbo/ebo in bias slot)
    f16x8 oDW[2], oEW;
#pragma unroll
    for (int kt = 0; kt < 2; ++kt)
#pragma unroll
      for (int e = 0; e < 8; ++e) {
        const int k = 32*kt + 8*g + e;
        float v = 0.0f;
        if (p == 0) v = (k < 50) ? sm[OFF_DWO + k]
                                 : (k == 50 ? sm[OFF_SC] : 0.0f);
        oDW[kt][e] = (f16)v;
      }
#pragma unroll
    for (int e = 0; e < 8; ++e) {
      const int k = 8*g + e;
      float v = 0.0f;
      if (p == 0) v = (k < 20) ? sm[OFF_EWO + k]
                               : (k == 31 ? sm[OFF_SC + 1] : 0.0f);
      oEW[e] = (f16)v;
    }

    // accCur for period m (m=0: from S0; m>0: recompute from path history,
    // bit-identical k-order)
#pragma unroll
    for (int e = 0; e < 8; ++e)
      accCur[e] = S0v * sm[OFF_EWI + 20 + 8*g + e];
    const int kmax = 30*m;
    for (int k = 1; k <= kmax; ++k) {
      const float Sk = ph[p*62 + k];
      const int ro = (1 + k)*20 + 8*g;
      const f32x4 w0 = *(const f32x4*)&sm[OFF_EWI + ro];
      const f32x4 w1 = *(const f32x4*)&sm[OFF_EWI + ro + 4];
#pragma unroll
      for (int e = 0; e < 4; ++e) {
        accCur[e]   = fmaf(Sk, w0[e], accCur[e]);
        accCur[e+4] = fmaf(Sk, w1[e], accCur[e+4]);
      }
    }

    if (m == 0) {
      diff_L1(sm, acth, 0.0f, S, p, g);
      mfma_hidden_r(dA[0], acth, p, g);
      mfma_hidden_r(dA[1], acth, p, g);
      mfma_hidden_l(smh + DWH_F + 8192, acth, p, g);
      const float d0 = diff_out_m(oDW, acth, p, g);
      if (g == 0)
        out[VARP_OFF + (size_t)(P0 + p) * NGRID + 0] = d0 * d0;
      CFENCE();
    }

    for (int it = 1; it <= 30; ++it) {
      const int i = m*30 + it;
      const float ti = 0.01f * (float)i;
      const float tp = 0.01f * (float)(i - 1);
      const float hstep = ti - tp;
      const float sqh = sqrtf(hstep);
      const float disc = sm[OFF_DTAB + (i - 1)];
      const float zval = zg[(size_t)(P0 + p) * NSTEPS + (i - 1)];
      const float dWv = sqh * zval;

      // ---------------- small-net L1s ----------------
      { // vL1: rows 8g..8g+7 (row 31 -> 1.0 via VBI[31])
        const int j0 = 8*g;
        f16x8 vh;
#pragma unroll
        for (int c = 0; c < 2; ++c) {
          const f32x4 w0 = *(const f32x4*)&sm[OFF_VW0 + j0 + 4*c];
          const f32x4 w1 = *(const f32x4*)&sm[OFF_VW1 + j0 + 4*c];
          const f32x4 bi = *(const f32x4*)&sm[OFF_VBI + j0 + 4*c];
#pragma unroll
          for (int r = 0; r < 4; ++r)
            vh[c*4+r] = (f16)fmaxf(fmaf(w0[r], tp, fmaf(w1[r], S, bi[r])), 0.0f);
        }
        *(f16x8*)&vvact[p*40 + j0] = vh;
      }
      { // eL1: rows 8g..8g+7; row 31 forced to 1.0 (const slot)
        const int j0 = 8*g;
        const f32x4 t0 = *(const f32x4*)&sm[OFF_EWI + j0];
        const f32x4 t1 = *(const f32x4*)&sm[OFF_EWI + j0 + 4];
        const f32x4 b0 = *(const f32x4*)&sm[OFF_EBI + j0];
        const f32x4 b1 = *(const f32x4*)&sm[OFF_EBI + j0 + 4];
        f16x8 vh;
#pragma unroll
        for (int e = 0; e < 8; ++e) {
          const float wt = (e < 4) ? t0[e] : t1[e-4];
          const float bb = (e < 4) ? b0[e] : b1[e-4];
          float x = fmaxf(fmaf(wt, tp, accCur[e] + bb), 0.0f);
          if (j0 + e == 31) x = 1.0f;
          vh[e] = (f16)x;
        }
        *(f16x8*)&veact[p*40 + j0] = vh;
      }
      CFENCE();
      small_pair_r(vA1, eA1, vvact, veact, p, g);
      small_pair_r(vA2, eA2, vvact, veact, p, g);

      // ---------------- diff net ----------------
      diff_L1(sm, acth, tp, S, p, g);
      mfma_hidden_r(dA[0], acth, p, g);
      mfma_hidden_r(dA[1], acth, p, g);
      mfma_hidden_l(smh + DWH_F + 8192, acth, p, g);
      const float d = diff_out_m(oDW, acth, p, g);
      const float gg = ((disc * S) * d) * dWv;   // S is old S
      if (g == 0) {
        out[VARP_OFF + (size_t)(P0 + p) * NGRID + i] = d * d;
        if (i == NSTEPS) out[DL_OFF + (P0 + p)] = d;
      }

      // ---------------- vOut (bias in A slot 31) + cvv ----------------
      {
        const f16x8 Bv = *(const f16x8*)&vvact[p*40 + 8*g];
#pragma unroll
        for (int mt = 0; mt < 4; ++mt) {
          const f32x4 acc = __builtin_amdgcn_mfma_f32_16x16x32_f16(
              oA[mt], Bv, (f32x4){0.f,0.f,0.f,0.f}, 0,0,0);
#pragma unroll
          for (int r = 0; r < 4; ++r)
            cvv[mt][r] = fmaf(gg, acc[r], cvv[mt][r]);
        }
      }
      // ---------------- eOut via row-0 MFMA ----------------
      {
        const f16x8 Be = *(const f16x8*)&veact[p*40 + 8*g];
        const f32x4 acc = __builtin_amdgcn_mfma_f32_16x16x32_f16(
            oEW, Be, (f32x4){0.f,0.f,0.f,0.f}, 0,0,0);
        const float eouts = __shfl(acc[0], p);
        cve = fmaf(gg, eouts, cve);
      }

      // ---------------- state update ----------------
      const float Sold = S;
      const float t1_ = (RATEf*Sold*hstep) * fast_rcp(1.0f + (RATEf*Sold)*sqh);
      const float t2_ = ((Sold*d)*dWv)     * fast_rcp(1.0f + (Sold*d)*sqh);
      const float Snew = (Sold + t1_) + t2_;
      S = Snew;
      rmax = fmaxf(rmax, Snew);
      if (g == 0) {
        out[PATH_OFF + (size_t)(P0 + p) * NGRID + i] = Snew;
        if (i <= 60) ph[p*62 + i] = Snew;
      }
      { // incremental cve-L1 update, EWI row (1+i)
        const int ro = OFF_EWI + (1 + i)*20 + 8*g;
        const f32x4 a0 = *(const f32x4*)&sm[ro];
        const f32x4 a1 = *(const f32x4*)&sm[ro + 4];
#pragma unroll
        for (int e = 0; e < 4; ++e) {
          accCur[e]   = fmaf(Snew, a0[e], accCur[e]);
          accCur[e+4] = fmaf(Snew, a1[e], accCur[e+4]);
        }
      }
      CFENCE();
    } // steps

    // ---------------- period-end price partials ----------------
    {
      const float discm = sm[OFF_DTAB + 30*(m+1)];
      double* ps = (double*)&sm[OFF_PSUM];
#pragma unroll
      for (int mt = 0; mt < 4; ++mt) {
#pragma unroll
        for (int r = 0; r < 4; ++r) {
          const int s = 16*mt + 4*g + r;
          const bool act = (s >= 21*m) && (s < 21*m + 21);
          double s1 = 0.0, s2 = 0.0;
          if (act) {
            const float Kst = 0.8f + 0.02f * (float)(s - 21*m);
            const float pr_ = discm * fmaxf(S - Kst, 0.0f) - cvv[mt][r];
            s1 = (double)pr_;
            s2 = (double)pr_ * (double)pr_;
          }
          s1 += __shfl_xor(s1, 1); s1 += __shfl_xor(s1, 2);
          s1 += __shfl_xor(s1, 4); s1 += __shfl_xor(s1, 8);
          s2 += __shfl_xor(s2, 1); s2 += __shfl_xor(s2, 2);
          s2 += __shfl_xor(s2, 4); s2 += __shfl_xor(s2, 8);
          if (act && p == 0) {
            const int sI = s - 21*m;
            ps[wv*42 + sI*2 + 0] = s1;
            ps[wv*42 + sI*2 + 1] = s2;
          }
        }
      }
    }
    __syncthreads();
    if (tid < 21) {
      double* ps = (double*)&sm[OFF_PSUM];
      double a = 0.0, b = 0.0;
      for (int w = 0; w < 8; ++w) { a += ps[w*42 + tid*2]; b += ps[w*42 + tid*2 + 1]; }
      wsd[(size_t)blockIdx.x*WS_STRIDE + (m*21+tid)*2 + 0] = a;
      wsd[(size_t)blockIdx.x*WS_STRIDE + (m*21+tid)*2 + 1] = b;
    }
  } // periods

  // ---------------- exotic outputs & partials ----------------
  const float discT = sm[OFF_DTAB + 90];
  const float e  = discT * (rmax - S);
  const float ep = e - cve;
  if (g == 0) out[EP_OFF + (P0 + p)] = ep;
  double de  = (g == 0) ? (double)e  : 0.0;
  double dp  = (g == 0) ? (double)ep : 0.0;
  double dp2 = (g == 0) ? (double)ep * (double)ep : 0.0;
#pragma unroll
  for (int msk = 1; msk <= 32; msk <<= 1) {
    de  += __shfl_xor(de,  msk);
    dp  += __shfl_xor(dp,  msk);
    dp2 += __shfl_xor(dp2, msk);
  }
  {
    double* es = (double*)&sm[OFF_ESUM];
    if (lane == 0) { es[wv*4+0] = de; es[wv*4+1] = dp; es[wv*4+2] = dp2; }
  }
  __syncthreads();
  if (tid == 0) {
    double* es = (double*)&sm[OFF_ESUM];
    double a = 0, b = 0, c = 0;
    for (int w = 0; w < 8; ++w) { a += es[w*4]; b += es[w*4+1]; c += es[w*4+2]; }
    wsd[(size_t)blockIdx.x*WS_STRIDE + 126] = a;
    wsd[(size_t)blockIdx.x*WS_STRIDE + 127] = b;
    wsd[(size_t)blockIdx.x*WS_STRIDE + 128] = c;
  }
}

extern "C" __global__ void finalize_kernel(double* __restrict__ wsd,
                                           float* __restrict__ out)
{
  const int t = threadIdx.x;
  if (t < 63) {
    double a = 0.0, b = 0.0;
    for (int blk = 0; blk < NBLK; ++blk) {
      a += wsd[(size_t)blk*WS_STRIDE + t*2 + 0];
      b += wsd[(size_t)blk*WS_STRIDE + t*2 + 1];
    }
    const double mean = a / (double)MC;
    const double var  = (b - a*a/(double)MC) / (double)(MC - 1);
    out[PV_OFF + t] = (float)mean;
    out[VV_OFF + t] = (float)var;
  } else if (t == 64) {
    double a = 0.0;
    for (int blk = 0; blk < NBLK; ++blk) a += wsd[(size_t)blk*WS_STRIDE + 126];
    wsd[MEANE_SLOT] = a / (double)MC;
  } else if (t == 65) {
    double a = 0.0, c = 0.0;
    for (int blk = 0; blk < NBLK; ++blk) {
      a += wsd[(size_t)blk*WS_STRIDE + 127];
      c += wsd[(size_t)blk*WS_STRIDE + 128];
    }
    out[MEAN_OFF] = (float)(a / (double)MC);
    out[VAR_OFF]  = (float)((c - a*a/(double)MC) / (double)(MC - 1));
  }
}

extern "C" __global__ void error_kernel(const double* __restrict__ wsd,
                                        float* __restrict__ out)
{
  const int pth = blockIdx.x * 256 + threadIdx.x;
  if (pth < MC) {
    const float meanE = (float)wsd[MEANE_SLOT];
    out[ERR_OFF + pth] = out[EP_OFF + pth] - meanE;
  }
}

extern "C" void kernel_launch(void* const* d_in, const int* in_sizes, int n_in,
                              void* d_out, int out_size, void* d_ws, size_t ws_size,
                              hipStream_t stream)
{
  (void)in_sizes; (void)n_in; (void)out_size; (void)ws_size;
  const float* S0g  = (const float*)d_in[0];
  const float* zg   = (const float*)d_in[1];
  // d_in[2..4] = MC_samples / ind_T / period_length (fixed constants)
  const float* dWi  = (const float*)d_in[5];
  const float* dbi  = (const float*)d_in[6];
  const float* dWh  = (const float*)d_in[7];
  const float* dbh  = (const float*)d_in[8];
  const float* dWo  = (const float*)d_in[9];
  const float* dbo  = (const float*)d_in[10];
  const float* vWi  = (const float*)d_in[11];
  const float* vbi  = (const float*)d_in[12];
  const float* vWh  = (const float*)d_in[13];
  const float* vbh  = (const float*)d_in[14];
  const float* vWo  = (const float*)d_in[15];
  const float* vbo  = (const float*)d_in[16];
  const float* eWi  = (const float*)d_in[17];
  const float* ebi  = (const float*)d_in[18];
  const float* eWh  = (const float*)d_in[19];
  const float* ebh  = (const float*)d_in[20];
  const float* eWo  = (const float*)d_in[21];
  const float* ebo  = (const float*)d_in[22];
  float* out  = (float*)d_out;
  double* wsd = (double*)d_ws;

  hipFuncSetAttribute(reinterpret_cast<const void*>(sim_kernel),
                      hipFuncAttributeMaxDynamicSharedMemorySize, SMEM_BYTES);

  sim_kernel<<<NBLK, TPB, SMEM_BYTES, stream>>>(
      S0g, zg, dWi, dbi, dWh, dbh, dWo, dbo,
      vWi, vbi, vWh, vbh, vWo, vbo,
      eWi, ebi, eWh, ebh, eWo, ebo, out, wsd);
  finalize_kernel<<<1, 128, 0, stream>>>(wsd, out);
  error_kernel<<<MC/256, 256, 0, stream>>>(wsd, out);
}